// Round 1
// baseline (946.474 us; speedup 1.0000x reference)
//
#include <hip/hip_runtime.h>
#include <hip/hip_bf16.h>

#define N_NODES 100000
#define N_EDGES 800000
#define N_GRAPHS 512
#define D 128
#define EPSV 1e-5f
#define BR 32
#define KT 32

__device__ __forceinline__ float relu_f(float x){ return fmaxf(x, 0.0f); }

// ---------------- degree + per-graph node counts ----------------
__global__ __launch_bounds__(256) void k_deg(const int* __restrict__ dst,
                                             const int* __restrict__ batch,
                                             int* __restrict__ deg_i,
                                             float* __restrict__ cnt)
{
    int tid = blockIdx.x * blockDim.x + threadIdx.x;
    int stride = gridDim.x * blockDim.x;
    for (int e = tid; e < N_EDGES; e += stride)
        atomicAdd(&deg_i[dst[e]], 1);
    for (int i = tid; i < N_NODES; i += stride)
        atomicAdd(&cnt[batch[i]], 1.0f);
}

__global__ __launch_bounds__(256) void k_dinv(const int* __restrict__ deg_i,
                                              float* __restrict__ dinv,
                                              float* __restrict__ selfw)
{
    int i = blockIdx.x * blockDim.x + threadIdx.x;
    if (i < N_NODES){
        float d = (float)(deg_i[i] + 1);
        dinv[i]  = rsqrtf(d);
        selfw[i] = 1.0f / d;
    }
}

// ---------------- exclusive scan of deg_i -> row_ptr (3 passes) ----------------
__global__ __launch_bounds__(256) void k_scan1(const int* __restrict__ deg_i,
                                               int* __restrict__ partials)
{
    __shared__ int sd[256];
    int base = blockIdx.x * 1024 + threadIdx.x * 4;
    int4 v = make_int4(0,0,0,0);
    if (base + 4 <= N_NODES) v = *(const int4*)(deg_i + base);
    sd[threadIdx.x] = v.x + v.y + v.z + v.w;
    __syncthreads();
    for (int off = 128; off > 0; off >>= 1){
        if (threadIdx.x < off) sd[threadIdx.x] += sd[threadIdx.x + off];
        __syncthreads();
    }
    if (threadIdx.x == 0) partials[blockIdx.x] = sd[0];
}

__global__ __launch_bounds__(256) void k_scan2(int* __restrict__ partials,
                                               int* __restrict__ row_ptr)
{
    __shared__ int sd[256];
    int tid = threadIdx.x;
    int v = (tid < 98) ? partials[tid] : 0;
    sd[tid] = v;
    __syncthreads();
    for (int off = 1; off < 256; off <<= 1){
        int t = (tid >= off) ? sd[tid - off] : 0;
        __syncthreads();
        sd[tid] += t;
        __syncthreads();
    }
    if (tid < 98) partials[tid] = sd[tid] - v;
    if (tid == 0) row_ptr[N_NODES] = N_EDGES;
}

__global__ __launch_bounds__(256) void k_scan3(const int* __restrict__ deg_i,
                                               const int* __restrict__ partials,
                                               int* __restrict__ row_ptr)
{
    __shared__ int sd[256];
    int tid = threadIdx.x;
    int base = blockIdx.x * 1024 + tid * 4;
    int4 v = make_int4(0,0,0,0);
    if (base + 4 <= N_NODES) v = *(const int4*)(deg_i + base);
    int s = v.x + v.y + v.z + v.w;
    sd[tid] = s;
    __syncthreads();
    for (int off = 1; off < 256; off <<= 1){
        int t = (tid >= off) ? sd[tid - off] : 0;
        __syncthreads();
        sd[tid] += t;
        __syncthreads();
    }
    if (base + 4 <= N_NODES){
        int excl = sd[tid] - s + partials[blockIdx.x];
        int4 o;
        o.x = excl;
        o.y = o.x + v.x;
        o.z = o.y + v.y;
        o.w = o.z + v.z;
        *(int4*)(row_ptr + base) = o;
    }
}

// ---------------- CSR fill (edge -> slot under its dst row) ----------------
__global__ __launch_bounds__(256) void k_fill(const int* __restrict__ src,
                                              const int* __restrict__ dstA,
                                              const float* __restrict__ dinv,
                                              int* __restrict__ cursor,
                                              int* __restrict__ csr_src,
                                              float* __restrict__ csr_w)
{
    int tid = blockIdx.x * blockDim.x + threadIdx.x;
    int stride = gridDim.x * blockDim.x;
    for (int e = tid; e < N_EDGES; e += stride){
        int s = src[e], d = dstA[e];
        int pos = atomicAdd(&cursor[d], 1);
        csr_src[pos] = s;
        csr_w[pos]   = dinv[s] * dinv[d];
    }
}

// ---------------- fp32 GEMM: out[N,128] = f(A)[N,128] @ W[128,128] ----------------
// f = optional BN(scale,shift)+ReLU applied on load (fused from previous layer).
// 256 thr: tx=tid&15 -> cols {4tx..4tx+3, 64+4tx..+3}; ty=tid>>4 -> rows {2ty,2ty+1}.
__global__ __launch_bounds__(256) void k_gemm(const float* __restrict__ A,
                                              const float* __restrict__ W,
                                              const float* __restrict__ scale,
                                              const float* __restrict__ shift,
                                              float* __restrict__ out,
                                              int useBn)
{
    __shared__ float ws[KT][D];        // 16 KB
    __shared__ float hs[BR][KT + 4];   // pad 4: ty-stride 72 floats -> banks 8 apart
    int tid = threadIdx.x;
    int tx = tid & 15, ty = tid >> 4;
    long long rowBase = (long long)blockIdx.x * BR;
    float acc[2][8];
    #pragma unroll
    for (int r = 0; r < 2; r++)
        #pragma unroll
        for (int j = 0; j < 8; j++) acc[r][j] = 0.f;

    for (int k0 = 0; k0 < D; k0 += KT){
        // stage W panel (KT x 128)
        #pragma unroll
        for (int j = 0; j < 4; j++){
            int f4 = tid + 256 * j;
            int kk = f4 >> 5;
            int cc = (f4 & 31) << 2;
            *(float4*)&ws[kk][cc] = *(const float4*)(W + (k0 + kk) * D + cc);
        }
        // stage A panel (BR x KT) with fused BN+ReLU
        {
            int r  = tid >> 3;
            int cc = (tid & 7) << 2;
            float4 v = *(const float4*)(A + (rowBase + r) * D + k0 + cc);
            if (useBn){
                float4 sc = *(const float4*)(scale + k0 + cc);
                float4 sh = *(const float4*)(shift + k0 + cc);
                v.x = relu_f(fmaf(v.x, sc.x, sh.x));
                v.y = relu_f(fmaf(v.y, sc.y, sh.y));
                v.z = relu_f(fmaf(v.z, sc.z, sh.z));
                v.w = relu_f(fmaf(v.w, sc.w, sh.w));
            }
            *(float4*)&hs[r][cc] = v;
        }
        __syncthreads();
        #pragma unroll
        for (int k = 0; k < KT; k++){
            float4 w0 = *(const float4*)&ws[k][4 * tx];
            float4 w1 = *(const float4*)&ws[k][64 + 4 * tx];
            float a0 = hs[2 * ty][k];
            float a1 = hs[2 * ty + 1][k];
            acc[0][0] = fmaf(a0, w0.x, acc[0][0]);
            acc[0][1] = fmaf(a0, w0.y, acc[0][1]);
            acc[0][2] = fmaf(a0, w0.z, acc[0][2]);
            acc[0][3] = fmaf(a0, w0.w, acc[0][3]);
            acc[0][4] = fmaf(a0, w1.x, acc[0][4]);
            acc[0][5] = fmaf(a0, w1.y, acc[0][5]);
            acc[0][6] = fmaf(a0, w1.z, acc[0][6]);
            acc[0][7] = fmaf(a0, w1.w, acc[0][7]);
            acc[1][0] = fmaf(a1, w0.x, acc[1][0]);
            acc[1][1] = fmaf(a1, w0.y, acc[1][1]);
            acc[1][2] = fmaf(a1, w0.z, acc[1][2]);
            acc[1][3] = fmaf(a1, w0.w, acc[1][3]);
            acc[1][4] = fmaf(a1, w1.x, acc[1][4]);
            acc[1][5] = fmaf(a1, w1.y, acc[1][5]);
            acc[1][6] = fmaf(a1, w1.z, acc[1][6]);
            acc[1][7] = fmaf(a1, w1.w, acc[1][7]);
        }
        __syncthreads();
    }
    #pragma unroll
    for (int r = 0; r < 2; r++){
        long long row = rowBase + 2 * ty + r;
        float4 o0 = make_float4(acc[r][0], acc[r][1], acc[r][2], acc[r][3]);
        float4 o1 = make_float4(acc[r][4], acc[r][5], acc[r][6], acc[r][7]);
        *(float4*)(out + row * D + 4 * tx)      = o0;
        *(float4*)(out + row * D + 64 + 4 * tx) = o1;
    }
}

// ---------------- edge aggregation + bias + BN-stat accumulation ----------------
// wave per node (grid-stride); lane holds features {2l, 2l+1}.
__global__ __launch_bounds__(256) void k_agg(const float* __restrict__ t,
                                             const int* __restrict__ row_ptr,
                                             const int* __restrict__ csr_src,
                                             const float* __restrict__ csr_w,
                                             const float* __restrict__ selfw,
                                             const float* __restrict__ bias,
                                             float* __restrict__ outb,
                                             float* __restrict__ S,
                                             float* __restrict__ Q)
{
    __shared__ float ldsS[4][128];
    __shared__ float ldsQ[4][128];
    int lane = threadIdx.x & 63;
    int wv   = threadIdx.x >> 6;
    int wave = blockIdx.x * 4 + wv;
    int nwaves = gridDim.x * 4;
    const float2* t2 = (const float2*)t;
    float2* o2 = (float2*)outb;
    float2 b2 = ((const float2*)bias)[lane];
    float sx = 0.f, sy = 0.f, qx = 0.f, qy = 0.f;
    for (int i = wave; i < N_NODES; i += nwaves){
        int p0 = row_ptr[i], p1 = row_ptr[i + 1];
        float sw = selfw[i];
        float2 a = t2[i * 64 + lane];
        float ax = a.x * sw, ay = a.y * sw;
        for (int p = p0; p < p1; ++p){
            int s   = csr_src[p];
            float w = csr_w[p];
            float2 v = t2[s * 64 + lane];
            ax = fmaf(w, v.x, ax);
            ay = fmaf(w, v.y, ay);
        }
        ax += b2.x; ay += b2.y;
        float2 o; o.x = ax; o.y = ay;
        o2[i * 64 + lane] = o;
        sx += ax; sy += ay;
        qx = fmaf(ax, ax, qx);
        qy = fmaf(ay, ay, qy);
    }
    ldsS[wv][2 * lane] = sx;  ldsS[wv][2 * lane + 1] = sy;
    ldsQ[wv][2 * lane] = qx;  ldsQ[wv][2 * lane + 1] = qy;
    __syncthreads();
    int tid = threadIdx.x;
    if (tid < 128){
        float s = ldsS[0][tid] + ldsS[1][tid] + ldsS[2][tid] + ldsS[3][tid];
        atomicAdd(&S[tid], s);
    } else {
        int f = tid - 128;
        float q = ldsQ[0][f] + ldsQ[1][f] + ldsQ[2][f] + ldsQ[3][f];
        atomicAdd(&Q[f], q);
    }
}

// ---------------- BN finalize: per-feature scale/shift ----------------
__global__ __launch_bounds__(128) void k_fin(const float* __restrict__ S,
                                             const float* __restrict__ Q,
                                             const float* __restrict__ gamma,
                                             const float* __restrict__ beta,
                                             float* __restrict__ sc,
                                             float* __restrict__ sh)
{
    int f = threadIdx.x;
    float mean = S[f] * (1.0f / N_NODES);
    float var  = fmaxf(Q[f] * (1.0f / N_NODES) - mean * mean, 0.0f);
    float inv  = rsqrtf(var + EPSV);
    float g = gamma[f] * inv;
    sc[f] = g;
    sh[f] = beta[f] - mean * g;
}

// ---------------- pooled sum per graph (batch sorted -> run-accumulate) ----------------
#define CHUNK 64
__global__ __launch_bounds__(256) void k_pool(const float* __restrict__ h,
                                              const int* __restrict__ batch,
                                              const float* __restrict__ sc,
                                              const float* __restrict__ sh,
                                              float* __restrict__ pool)
{
    int lane = threadIdx.x & 63;
    int wave = (blockIdx.x * blockDim.x + threadIdx.x) >> 6;
    int i0 = wave * CHUNK;
    if (i0 >= N_NODES) return;
    int i1 = min(N_NODES, i0 + CHUNK);
    const float2* h2 = (const float2*)h;
    float2 scv = ((const float2*)sc)[lane];
    float2 shv = ((const float2*)sh)[lane];
    int g = batch[i0];
    float ax = 0.f, ay = 0.f;
    for (int i = i0; i < i1; ++i){
        int gi = batch[i];
        if (gi != g){
            atomicAdd(&pool[g * 128 + 2 * lane],     ax);
            atomicAdd(&pool[g * 128 + 2 * lane + 1], ay);
            ax = 0.f; ay = 0.f; g = gi;
        }
        float2 v = h2[i * 64 + lane];
        ax += relu_f(fmaf(v.x, scv.x, shv.x));
        ay += relu_f(fmaf(v.y, scv.y, shv.y));
    }
    atomicAdd(&pool[g * 128 + 2 * lane],     ax);
    atomicAdd(&pool[g * 128 + 2 * lane + 1], ay);
}

// ---------------- MLP head: one block per graph ----------------
__global__ __launch_bounds__(128) void k_head(const float* __restrict__ pool,
                                              const float* __restrict__ cnt,
                                              const float* __restrict__ W1,
                                              const float* __restrict__ b1,
                                              const float* __restrict__ W2,
                                              const float* __restrict__ b2,
                                              float* __restrict__ out)
{
    __shared__ float z[128];
    __shared__ float red[128];
    int g = blockIdx.x, f = threadIdx.x;
    float c = fmaxf(cnt[g], 1.0f);
    z[f] = pool[g * 128 + f] / c;
    __syncthreads();
    float a = b1[f];
    #pragma unroll 8
    for (int k = 0; k < 128; k++)
        a = fmaf(z[k], W1[k * 128 + f], a);
    a = relu_f(a);
    red[f] = a * W2[f];
    __syncthreads();
    for (int s2 = 64; s2 > 0; s2 >>= 1){
        if (f < s2) red[f] += red[f + s2];
        __syncthreads();
    }
    if (f == 0) out[g] = red[0] + b2[0];
}

extern "C" void kernel_launch(void* const* d_in, const int* in_sizes, int n_in,
                              void* d_out, int out_size, void* d_ws, size_t ws_size,
                              hipStream_t stream)
{
    const float* x      = (const float*)d_in[0];
    const int*   ei     = (const int*)d_in[1];
    const int*   batch  = (const int*)d_in[2];
    const float* Ws     = (const float*)d_in[3];
    const float* bs     = (const float*)d_in[4];
    const float* gammas = (const float*)d_in[5];
    const float* betas  = (const float*)d_in[6];
    const float* W1     = (const float*)d_in[7];
    const float* b1     = (const float*)d_in[8];
    const float* W2     = (const float*)d_in[9];
    const float* b2     = (const float*)d_in[10];
    float* out = (float*)d_out;

    const int* src = ei;
    const int* dst = ei + N_EDGES;

    char* w = (char*)d_ws;
    size_t off = 0;
    auto alloc = [&](size_t bytes) -> void* {
        void* p = w + off;
        off += (bytes + 255) & ~(size_t)255;
        return p;
    };
    int*   deg_i    = (int*)  alloc((size_t)N_NODES * 4);
    int*   row_ptr  = (int*)  alloc((size_t)(N_NODES + 1) * 4);
    int*   cursor   = (int*)  alloc((size_t)N_NODES * 4);
    float* dinv     = (float*)alloc((size_t)N_NODES * 4);
    float* selfw    = (float*)alloc((size_t)N_NODES * 4);
    int*   csr_src  = (int*)  alloc((size_t)N_EDGES * 4);
    float* csr_w    = (float*)alloc((size_t)N_EDGES * 4);
    int*   partials = (int*)  alloc(128 * 4);
    size_t zoff = off;                       // --- zero-span start ---
    float* stats    = (float*)alloc(3 * 256 * 4);      // per layer: S @ l*256, Q @ l*256+128
    float* pool     = (float*)alloc((size_t)N_GRAPHS * 128 * 4);
    float* cnt      = (float*)alloc((size_t)N_GRAPHS * 4);
    size_t zend = off;                       // --- zero-span end ---
    float* ssh      = (float*)alloc(3 * 256 * 4);      // per layer: scale @ l*256, shift @ +128
    float* bufA     = (float*)alloc((size_t)N_NODES * 128 * 4);
    float* bufB     = (float*)alloc((size_t)N_NODES * 128 * 4);
    if (off > ws_size) return;  // workspace too small — fail loudly via wrong output

    hipMemsetAsync(deg_i, 0, (size_t)N_NODES * 4, stream);
    hipMemsetAsync(w + zoff, 0, zend - zoff, stream);

    k_deg <<<3125, 256, 0, stream>>>(dst, batch, deg_i, cnt);
    k_dinv<<<(N_NODES + 255) / 256, 256, 0, stream>>>(deg_i, dinv, selfw);
    k_scan1<<<98, 256, 0, stream>>>(deg_i, partials);
    k_scan2<<<1, 256, 0, stream>>>(partials, row_ptr);
    k_scan3<<<98, 256, 0, stream>>>(deg_i, partials, row_ptr);
    hipMemcpyAsync(cursor, row_ptr, (size_t)N_NODES * 4, hipMemcpyDeviceToDevice, stream);
    k_fill<<<3125, 256, 0, stream>>>(src, dst, dinv, cursor, csr_src, csr_w);

    const float* curIn = x;
    for (int l = 0; l < 3; l++){
        k_gemm<<<N_NODES / BR, 256, 0, stream>>>(
            curIn, Ws + l * 128 * 128,
            l ? ssh + (l - 1) * 256       : nullptr,
            l ? ssh + (l - 1) * 256 + 128 : nullptr,
            bufA, l ? 1 : 0);
        k_agg<<<1024, 256, 0, stream>>>(
            bufA, row_ptr, csr_src, csr_w, selfw,
            bs + l * 128, bufB, stats + l * 256, stats + l * 256 + 128);
        k_fin<<<1, 128, 0, stream>>>(
            stats + l * 256, stats + l * 256 + 128,
            gammas + l * 128, betas + l * 128,
            ssh + l * 256, ssh + l * 256 + 128);
        curIn = bufB;
    }

    k_pool<<<391, 256, 0, stream>>>(bufB, batch, ssh + 2 * 256, ssh + 2 * 256 + 128, pool);
    k_head<<<512, 128, 0, stream>>>(pool, cnt, W1, b1, W2, b2, out);
}

// Round 2
// 757.274 us; speedup vs baseline: 1.2498x; 1.2498x over previous
//
#include <hip/hip_runtime.h>
#include <hip/hip_bf16.h>

#define N_NODES 100000
#define N_EDGES 800000
#define N_GRAPHS 512
#define D 128
#define EPSV 1e-5f
#define BR 32
#define KT 32

__device__ __forceinline__ float relu_f(float x){ return fmaxf(x, 0.0f); }

// ---------------- degree + per-graph node counts ----------------
__global__ __launch_bounds__(256) void k_deg(const int* __restrict__ dst,
                                             const int* __restrict__ batch,
                                             int* __restrict__ deg_i,
                                             float* __restrict__ cnt)
{
    int tid = blockIdx.x * blockDim.x + threadIdx.x;
    int stride = gridDim.x * blockDim.x;
    for (int e = tid; e < N_EDGES; e += stride)
        atomicAdd(&deg_i[dst[e]], 1);
    for (int i = tid; i < N_NODES; i += stride)
        atomicAdd(&cnt[batch[i]], 1.0f);
}

__global__ __launch_bounds__(256) void k_dinv(const int* __restrict__ deg_i,
                                              float* __restrict__ dinv,
                                              float* __restrict__ selfw)
{
    int i = blockIdx.x * blockDim.x + threadIdx.x;
    if (i < N_NODES){
        float d = (float)(deg_i[i] + 1);
        dinv[i]  = rsqrtf(d);
        selfw[i] = 1.0f / d;
    }
}

// ---------------- exclusive scan of deg_i -> row_ptr (3 passes) ----------------
__global__ __launch_bounds__(256) void k_scan1(const int* __restrict__ deg_i,
                                               int* __restrict__ partials)
{
    __shared__ int sd[256];
    int base = blockIdx.x * 1024 + threadIdx.x * 4;
    int4 v = make_int4(0,0,0,0);
    if (base + 4 <= N_NODES) v = *(const int4*)(deg_i + base);
    sd[threadIdx.x] = v.x + v.y + v.z + v.w;
    __syncthreads();
    for (int off = 128; off > 0; off >>= 1){
        if (threadIdx.x < off) sd[threadIdx.x] += sd[threadIdx.x + off];
        __syncthreads();
    }
    if (threadIdx.x == 0) partials[blockIdx.x] = sd[0];
}

__global__ __launch_bounds__(256) void k_scan2(int* __restrict__ partials,
                                               int* __restrict__ row_ptr)
{
    __shared__ int sd[256];
    int tid = threadIdx.x;
    int v = (tid < 98) ? partials[tid] : 0;
    sd[tid] = v;
    __syncthreads();
    for (int off = 1; off < 256; off <<= 1){
        int t = (tid >= off) ? sd[tid - off] : 0;
        __syncthreads();
        sd[tid] += t;
        __syncthreads();
    }
    if (tid < 98) partials[tid] = sd[tid] - v;
    if (tid == 0) row_ptr[N_NODES] = N_EDGES;
}

__global__ __launch_bounds__(256) void k_scan3(const int* __restrict__ deg_i,
                                               const int* __restrict__ partials,
                                               int* __restrict__ row_ptr)
{
    __shared__ int sd[256];
    int tid = threadIdx.x;
    int base = blockIdx.x * 1024 + tid * 4;
    int4 v = make_int4(0,0,0,0);
    if (base + 4 <= N_NODES) v = *(const int4*)(deg_i + base);
    int s = v.x + v.y + v.z + v.w;
    sd[tid] = s;
    __syncthreads();
    for (int off = 1; off < 256; off <<= 1){
        int t = (tid >= off) ? sd[tid - off] : 0;
        __syncthreads();
        sd[tid] += t;
        __syncthreads();
    }
    if (base + 4 <= N_NODES){
        int excl = sd[tid] - s + partials[blockIdx.x];
        int4 o;
        o.x = excl;
        o.y = o.x + v.x;
        o.z = o.y + v.y;
        o.w = o.z + v.z;
        *(int4*)(row_ptr + base) = o;
    }
}

// ---------------- CSR fill (edge -> slot under its dst row) ----------------
__global__ __launch_bounds__(256) void k_fill(const int* __restrict__ src,
                                              const int* __restrict__ dstA,
                                              const float* __restrict__ dinv,
                                              int* __restrict__ cursor,
                                              int* __restrict__ csr_src,
                                              float* __restrict__ csr_w)
{
    int tid = blockIdx.x * blockDim.x + threadIdx.x;
    int stride = gridDim.x * blockDim.x;
    for (int e = tid; e < N_EDGES; e += stride){
        int s = src[e], d = dstA[e];
        int pos = atomicAdd(&cursor[d], 1);
        csr_src[pos] = s;
        csr_w[pos]   = dinv[s] * dinv[d];
    }
}

// ---------------- fp32 GEMM: out[N,128] = f(A)[N,128] @ W[128,128] ----------------
__global__ __launch_bounds__(256) void k_gemm(const float* __restrict__ A,
                                              const float* __restrict__ W,
                                              const float* __restrict__ scale,
                                              const float* __restrict__ shift,
                                              float* __restrict__ out,
                                              int useBn)
{
    __shared__ float ws[KT][D];        // 16 KB
    __shared__ float hs[BR][KT + 4];
    int tid = threadIdx.x;
    int tx = tid & 15, ty = tid >> 4;
    long long rowBase = (long long)blockIdx.x * BR;
    float acc[2][8];
    #pragma unroll
    for (int r = 0; r < 2; r++)
        #pragma unroll
        for (int j = 0; j < 8; j++) acc[r][j] = 0.f;

    for (int k0 = 0; k0 < D; k0 += KT){
        #pragma unroll
        for (int j = 0; j < 4; j++){
            int f4 = tid + 256 * j;
            int kk = f4 >> 5;
            int cc = (f4 & 31) << 2;
            *(float4*)&ws[kk][cc] = *(const float4*)(W + (k0 + kk) * D + cc);
        }
        {
            int r  = tid >> 3;
            int cc = (tid & 7) << 2;
            float4 v = *(const float4*)(A + (rowBase + r) * D + k0 + cc);
            if (useBn){
                float4 sc = *(const float4*)(scale + k0 + cc);
                float4 sh = *(const float4*)(shift + k0 + cc);
                v.x = relu_f(fmaf(v.x, sc.x, sh.x));
                v.y = relu_f(fmaf(v.y, sc.y, sh.y));
                v.z = relu_f(fmaf(v.z, sc.z, sh.z));
                v.w = relu_f(fmaf(v.w, sc.w, sh.w));
            }
            *(float4*)&hs[r][cc] = v;
        }
        __syncthreads();
        #pragma unroll
        for (int k = 0; k < KT; k++){
            float4 w0 = *(const float4*)&ws[k][4 * tx];
            float4 w1 = *(const float4*)&ws[k][64 + 4 * tx];
            float a0 = hs[2 * ty][k];
            float a1 = hs[2 * ty + 1][k];
            acc[0][0] = fmaf(a0, w0.x, acc[0][0]);
            acc[0][1] = fmaf(a0, w0.y, acc[0][1]);
            acc[0][2] = fmaf(a0, w0.z, acc[0][2]);
            acc[0][3] = fmaf(a0, w0.w, acc[0][3]);
            acc[0][4] = fmaf(a0, w1.x, acc[0][4]);
            acc[0][5] = fmaf(a0, w1.y, acc[0][5]);
            acc[0][6] = fmaf(a0, w1.z, acc[0][6]);
            acc[0][7] = fmaf(a0, w1.w, acc[0][7]);
            acc[1][0] = fmaf(a1, w0.x, acc[1][0]);
            acc[1][1] = fmaf(a1, w0.y, acc[1][1]);
            acc[1][2] = fmaf(a1, w0.z, acc[1][2]);
            acc[1][3] = fmaf(a1, w0.w, acc[1][3]);
            acc[1][4] = fmaf(a1, w1.x, acc[1][4]);
            acc[1][5] = fmaf(a1, w1.y, acc[1][5]);
            acc[1][6] = fmaf(a1, w1.z, acc[1][6]);
            acc[1][7] = fmaf(a1, w1.w, acc[1][7]);
        }
        __syncthreads();
    }
    #pragma unroll
    for (int r = 0; r < 2; r++){
        long long row = rowBase + 2 * ty + r;
        float4 o0 = make_float4(acc[r][0], acc[r][1], acc[r][2], acc[r][3]);
        float4 o1 = make_float4(acc[r][4], acc[r][5], acc[r][6], acc[r][7]);
        *(float4*)(out + row * D + 4 * tx)      = o0;
        *(float4*)(out + row * D + 64 + 4 * tx) = o1;
    }
}

// ---------------- edge aggregation + bias (NO stats; one wave per node) ----------------
// Latency-bound fix: 4 independent gathers in flight per wave, 100K waves.
__global__ __launch_bounds__(256) void k_agg(const float* __restrict__ t,
                                             const int* __restrict__ row_ptr,
                                             const int* __restrict__ csr_src,
                                             const float* __restrict__ csr_w,
                                             const float* __restrict__ selfw,
                                             const float* __restrict__ bias,
                                             float* __restrict__ outb)
{
    int lane = threadIdx.x & 63;
    int i = (blockIdx.x * blockDim.x + threadIdx.x) >> 6;   // node = wave id
    if (i >= N_NODES) return;
    const float2* t2 = (const float2*)t;
    int p0 = row_ptr[i], p1 = row_ptr[i + 1];
    float sw = selfw[i];
    float2 a = t2[(size_t)i * 64 + lane];
    float ax = a.x * sw, ay = a.y * sw;
    int p = p0;
    for (; p + 4 <= p1; p += 4){
        int   s0 = csr_src[p],   s1 = csr_src[p+1], s2 = csr_src[p+2], s3 = csr_src[p+3];
        float w0 = csr_w[p],     w1 = csr_w[p+1],   w2 = csr_w[p+2],   w3 = csr_w[p+3];
        float2 v0 = t2[(size_t)s0 * 64 + lane];
        float2 v1 = t2[(size_t)s1 * 64 + lane];
        float2 v2 = t2[(size_t)s2 * 64 + lane];
        float2 v3 = t2[(size_t)s3 * 64 + lane];
        ax = fmaf(w0, v0.x, ax); ay = fmaf(w0, v0.y, ay);
        ax = fmaf(w1, v1.x, ax); ay = fmaf(w1, v1.y, ay);
        ax = fmaf(w2, v2.x, ax); ay = fmaf(w2, v2.y, ay);
        ax = fmaf(w3, v3.x, ax); ay = fmaf(w3, v3.y, ay);
    }
    for (; p < p1; ++p){
        int s = csr_src[p];
        float w = csr_w[p];
        float2 v = t2[(size_t)s * 64 + lane];
        ax = fmaf(w, v.x, ax);
        ay = fmaf(w, v.y, ay);
    }
    float2 b2 = ((const float2*)bias)[lane];
    float2 o; o.x = ax + b2.x; o.y = ay + b2.y;
    ((float2*)outb)[(size_t)i * 64 + lane] = o;
}

// ---------------- BN stats: streaming scan of h -> S, Q ----------------
__global__ __launch_bounds__(256) void k_stats(const float* __restrict__ h,
                                               float* __restrict__ S,
                                               float* __restrict__ Q)
{
    __shared__ float sS[8][128];
    __shared__ float sQ[8][128];
    int g  = threadIdx.x >> 5;   // 0..7 row group
    int c4 = threadIdx.x & 31;   // which float4 of the row
    int r0 = blockIdx.x * 400;
    const float4* h4 = (const float4*)h;   // row stride = 32 float4
    float4 s = make_float4(0.f, 0.f, 0.f, 0.f);
    float4 q = make_float4(0.f, 0.f, 0.f, 0.f);
    for (int r = r0 + g; r < r0 + 400; r += 8){
        float4 v = h4[(size_t)r * 32 + c4];
        s.x += v.x; s.y += v.y; s.z += v.z; s.w += v.w;
        q.x = fmaf(v.x, v.x, q.x);
        q.y = fmaf(v.y, v.y, q.y);
        q.z = fmaf(v.z, v.z, q.z);
        q.w = fmaf(v.w, v.w, q.w);
    }
    *(float4*)&sS[g][c4 * 4] = s;
    *(float4*)&sQ[g][c4 * 4] = q;
    __syncthreads();
    int f = threadIdx.x;
    if (f < 128){
        float acc = 0.f;
        #pragma unroll
        for (int j = 0; j < 8; j++) acc += sS[j][f];
        atomicAdd(&S[f], acc);
    } else {
        int f2 = f - 128;
        float acc = 0.f;
        #pragma unroll
        for (int j = 0; j < 8; j++) acc += sQ[j][f2];
        atomicAdd(&Q[f2], acc);
    }
}

// ---------------- BN finalize: per-feature scale/shift ----------------
__global__ __launch_bounds__(128) void k_fin(const float* __restrict__ S,
                                             const float* __restrict__ Q,
                                             const float* __restrict__ gamma,
                                             const float* __restrict__ beta,
                                             float* __restrict__ sc,
                                             float* __restrict__ sh)
{
    int f = threadIdx.x;
    float mean = S[f] * (1.0f / N_NODES);
    float var  = fmaxf(Q[f] * (1.0f / N_NODES) - mean * mean, 0.0f);
    float inv  = rsqrtf(var + EPSV);
    float g = gamma[f] * inv;
    sc[f] = g;
    sh[f] = beta[f] - mean * g;
}

// ---------------- pooled sum per graph (batch sorted -> run-accumulate) ----------------
#define CHUNK 64
__global__ __launch_bounds__(256) void k_pool(const float* __restrict__ h,
                                              const int* __restrict__ batch,
                                              const float* __restrict__ sc,
                                              const float* __restrict__ sh,
                                              float* __restrict__ pool)
{
    int lane = threadIdx.x & 63;
    int wave = (blockIdx.x * blockDim.x + threadIdx.x) >> 6;
    int i0 = wave * CHUNK;
    if (i0 >= N_NODES) return;
    int i1 = min(N_NODES, i0 + CHUNK);
    const float2* h2 = (const float2*)h;
    float2 scv = ((const float2*)sc)[lane];
    float2 shv = ((const float2*)sh)[lane];
    int g = batch[i0];
    float ax = 0.f, ay = 0.f;
    for (int i = i0; i < i1; ++i){
        int gi = batch[i];
        if (gi != g){
            atomicAdd(&pool[g * 128 + 2 * lane],     ax);
            atomicAdd(&pool[g * 128 + 2 * lane + 1], ay);
            ax = 0.f; ay = 0.f; g = gi;
        }
        float2 v = h2[(size_t)i * 64 + lane];
        ax += relu_f(fmaf(v.x, scv.x, shv.x));
        ay += relu_f(fmaf(v.y, scv.y, shv.y));
    }
    atomicAdd(&pool[g * 128 + 2 * lane],     ax);
    atomicAdd(&pool[g * 128 + 2 * lane + 1], ay);
}

// ---------------- MLP head: one block per graph ----------------
__global__ __launch_bounds__(128) void k_head(const float* __restrict__ pool,
                                              const float* __restrict__ cnt,
                                              const float* __restrict__ W1,
                                              const float* __restrict__ b1,
                                              const float* __restrict__ W2,
                                              const float* __restrict__ b2,
                                              float* __restrict__ out)
{
    __shared__ float z[128];
    __shared__ float red[128];
    int g = blockIdx.x, f = threadIdx.x;
    float c = fmaxf(cnt[g], 1.0f);
    z[f] = pool[g * 128 + f] / c;
    __syncthreads();
    float a = b1[f];
    #pragma unroll 8
    for (int k = 0; k < 128; k++)
        a = fmaf(z[k], W1[k * 128 + f], a);
    a = relu_f(a);
    red[f] = a * W2[f];
    __syncthreads();
    for (int s2 = 64; s2 > 0; s2 >>= 1){
        if (f < s2) red[f] += red[f + s2];
        __syncthreads();
    }
    if (f == 0) out[g] = red[0] + b2[0];
}

extern "C" void kernel_launch(void* const* d_in, const int* in_sizes, int n_in,
                              void* d_out, int out_size, void* d_ws, size_t ws_size,
                              hipStream_t stream)
{
    const float* x      = (const float*)d_in[0];
    const int*   ei     = (const int*)d_in[1];
    const int*   batch  = (const int*)d_in[2];
    const float* Ws     = (const float*)d_in[3];
    const float* bs     = (const float*)d_in[4];
    const float* gammas = (const float*)d_in[5];
    const float* betas  = (const float*)d_in[6];
    const float* W1     = (const float*)d_in[7];
    const float* b1     = (const float*)d_in[8];
    const float* W2     = (const float*)d_in[9];
    const float* b2     = (const float*)d_in[10];
    float* out = (float*)d_out;

    const int* src = ei;
    const int* dst = ei + N_EDGES;

    char* w = (char*)d_ws;
    size_t off = 0;
    auto alloc = [&](size_t bytes) -> void* {
        void* p = w + off;
        off += (bytes + 255) & ~(size_t)255;
        return p;
    };
    int*   deg_i    = (int*)  alloc((size_t)N_NODES * 4);
    int*   row_ptr  = (int*)  alloc((size_t)(N_NODES + 1) * 4);
    int*   cursor   = (int*)  alloc((size_t)N_NODES * 4);
    float* dinv     = (float*)alloc((size_t)N_NODES * 4);
    float* selfw    = (float*)alloc((size_t)N_NODES * 4);
    int*   csr_src  = (int*)  alloc((size_t)N_EDGES * 4);
    float* csr_w    = (float*)alloc((size_t)N_EDGES * 4);
    int*   partials = (int*)  alloc(128 * 4);
    size_t zoff = off;                       // --- zero-span start ---
    float* stats    = (float*)alloc(3 * 256 * 4);      // per layer: S @ l*256, Q @ l*256+128
    float* pool     = (float*)alloc((size_t)N_GRAPHS * 128 * 4);
    float* cnt      = (float*)alloc((size_t)N_GRAPHS * 4);
    size_t zend = off;                       // --- zero-span end ---
    float* ssh      = (float*)alloc(3 * 256 * 4);      // per layer: scale @ l*256, shift @ +128
    float* bufA     = (float*)alloc((size_t)N_NODES * 128 * 4);
    float* bufB     = (float*)alloc((size_t)N_NODES * 128 * 4);
    if (off > ws_size) return;

    hipMemsetAsync(deg_i, 0, (size_t)N_NODES * 4, stream);
    hipMemsetAsync(w + zoff, 0, zend - zoff, stream);

    k_deg <<<3125, 256, 0, stream>>>(dst, batch, deg_i, cnt);
    k_dinv<<<(N_NODES + 255) / 256, 256, 0, stream>>>(deg_i, dinv, selfw);
    k_scan1<<<98, 256, 0, stream>>>(deg_i, partials);
    k_scan2<<<1, 256, 0, stream>>>(partials, row_ptr);
    k_scan3<<<98, 256, 0, stream>>>(deg_i, partials, row_ptr);
    hipMemcpyAsync(cursor, row_ptr, (size_t)N_NODES * 4, hipMemcpyDeviceToDevice, stream);
    k_fill<<<3125, 256, 0, stream>>>(src, dst, dinv, cursor, csr_src, csr_w);

    const float* curIn = x;
    for (int l = 0; l < 3; l++){
        k_gemm<<<N_NODES / BR, 256, 0, stream>>>(
            curIn, Ws + l * 128 * 128,
            l ? ssh + (l - 1) * 256       : nullptr,
            l ? ssh + (l - 1) * 256 + 128 : nullptr,
            bufA, l ? 1 : 0);
        k_agg<<<25000, 256, 0, stream>>>(
            bufA, row_ptr, csr_src, csr_w, selfw,
            bs + l * 128, bufB);
        k_stats<<<250, 256, 0, stream>>>(
            bufB, stats + l * 256, stats + l * 256 + 128);
        k_fin<<<1, 128, 0, stream>>>(
            stats + l * 256, stats + l * 256 + 128,
            gammas + l * 128, betas + l * 128,
            ssh + l * 256, ssh + l * 256 + 128);
        curIn = bufB;
    }

    k_pool<<<391, 256, 0, stream>>>(bufB, batch, ssh + 2 * 256, ssh + 2 * 256 + 128, pool);
    k_head<<<512, 128, 0, stream>>>(pool, cnt, W1, b1, W2, b2, out);
}

// Round 3
// 625.801 us; speedup vs baseline: 1.5124x; 1.2101x over previous
//
#include <hip/hip_runtime.h>
#include <hip/hip_bf16.h>

#define N_NODES 100000
#define N_EDGES 800000
#define N_GRAPHS 512
#define D 128
#define EPSV 1e-5f
#define BR 32
#define KT 32

// radix-bucket CSR build params
#define NBLK 256          // edge-partition blocks
#define EPB  3125         // edges per block (256*3125 = 800000 exactly)
#define NBUK 196          // ceil(100000/512) buckets of 512 nodes (dst>>9)
#define MAXB 6144         // per-bucket LDS stash cap (mean 4096, sigma~64)

__device__ __forceinline__ float relu_f(float x){ return fmaxf(x, 0.0f); }

// ---------------- P1: per-block bucket histogram (LDS only) ----------------
__global__ __launch_bounds__(256) void k_p1(const int* __restrict__ dst,
                                            int* __restrict__ blockHist)
{
    __shared__ int h[NBUK];
    int j = blockIdx.x, t = threadIdx.x;
    if (t < NBUK) h[t] = 0;
    __syncthreads();
    int e0 = j * EPB;
    for (int e = e0 + t; e < e0 + EPB; e += 256)
        atomicAdd(&h[dst[e] >> 9], 1);
    __syncthreads();
    if (t < NBUK) blockHist[j * NBUK + t] = h[t];
}

// ---------------- P2: column scans + bucket bases (single block) ----------------
__global__ __launch_bounds__(256) void k_p2(const int* __restrict__ blockHist,
                                            int* __restrict__ colScan,
                                            int* __restrict__ bucketBase,
                                            int* __restrict__ row_ptr)
{
    __shared__ int sd[256];
    int b = threadIdx.x;
    int run = 0;
    if (b < NBUK){
        for (int j = 0; j < NBLK; j++){
            int v = blockHist[j * NBUK + b];
            colScan[j * NBUK + b] = run;   // edges of bucket b in blocks < j
            run += v;
        }
    }
    sd[b] = (b < NBUK) ? run : 0;
    __syncthreads();
    for (int off = 1; off < 256; off <<= 1){
        int v = (b >= off) ? sd[b - off] : 0;
        __syncthreads();
        sd[b] += v;
        __syncthreads();
    }
    if (b < NBUK) bucketBase[b] = sd[b] - run;   // exclusive
    if (b == 0){
        bucketBase[NBUK] = N_EDGES;
        row_ptr[N_NODES] = N_EDGES;
    }
}

// ---------------- P3: scatter edges into bucket-sorted ebuf (LDS cursors) ------
__global__ __launch_bounds__(256) void k_p3(const int* __restrict__ src,
                                            const int* __restrict__ dst,
                                            const int* __restrict__ colScan,
                                            const int* __restrict__ bucketBase,
                                            int2* __restrict__ ebuf)
{
    __shared__ int cur[NBUK];
    int j = blockIdx.x, t = threadIdx.x;
    if (t < NBUK) cur[t] = bucketBase[t] + colScan[j * NBUK + t];
    __syncthreads();
    int e0 = j * EPB;
    for (int e = e0 + t; e < e0 + EPB; e += 256){
        int s = src[e], d = dst[e];
        int pos = atomicAdd(&cur[d >> 9], 1);
        int2 v; v.x = s; v.y = d;
        ebuf[pos] = v;
    }
}

// ---------------- P4: per-bucket counting sort -> deg, row_ptr, CSR ----------
__global__ __launch_bounds__(256) void k_p4(const int2* __restrict__ ebuf,
                                            const int* __restrict__ bucketBase,
                                            int* __restrict__ deg,
                                            int* __restrict__ row_ptr,
                                            int* __restrict__ csr_src,
                                            int* __restrict__ csr_dst)
{
    __shared__ int2 stash[MAXB];
    __shared__ int bins[512];
    __shared__ int sd[256];
    int b = blockIdx.x, t = threadIdx.x;
    int base = bucketBase[b];
    int cntb = bucketBase[b + 1] - base;
    bool st = (cntb <= MAXB);
    bins[t] = 0; bins[t + 256] = 0;
    __syncthreads();
    for (int i = t; i < cntb; i += 256){
        int2 ed = ebuf[base + i];
        if (st) stash[i] = ed;
        atomicAdd(&bins[ed.y & 511], 1);
    }
    __syncthreads();
    int a0 = bins[2 * t], a1 = bins[2 * t + 1];
    int ps = a0 + a1;
    sd[t] = ps;
    __syncthreads();
    for (int off = 1; off < 256; off <<= 1){
        int v = (t >= off) ? sd[t - off] : 0;
        __syncthreads();
        sd[t] += v;
        __syncthreads();
    }
    int pex  = sd[t] - ps;        // exclusive over bin pairs
    int off0 = pex, off1 = pex + a0;
    int node = b * 512 + 2 * t;
    if (node < N_NODES)     { deg[node]     = a0; row_ptr[node]     = base + off0; }
    if (node + 1 < N_NODES) { deg[node + 1] = a1; row_ptr[node + 1] = base + off1; }
    __syncthreads();
    bins[2 * t] = off0; bins[2 * t + 1] = off1;   // repurpose as cursors
    __syncthreads();
    for (int i = t; i < cntb; i += 256){
        int2 ed = st ? stash[i] : ebuf[base + i];
        int pos = atomicAdd(&bins[ed.y & 511], 1);
        csr_src[base + pos] = ed.x;
        csr_dst[base + pos] = ed.y;
    }
}

__global__ __launch_bounds__(256) void k_dinv(const int* __restrict__ deg_i,
                                              float* __restrict__ dinv,
                                              float* __restrict__ selfw)
{
    int i = blockIdx.x * blockDim.x + threadIdx.x;
    if (i < N_NODES){
        float d = (float)(deg_i[i] + 1);
        dinv[i]  = rsqrtf(d);
        selfw[i] = 1.0f / d;
    }
}

// ---------------- edge weights: w = dinv[src]*dinv[dst] ----------------
__global__ __launch_bounds__(256) void k_w(const int* __restrict__ csr_src,
                                           const int* __restrict__ csr_dst,
                                           const float* __restrict__ dinv,
                                           float* __restrict__ csr_w)
{
    int p = blockIdx.x * 256 + threadIdx.x;
    if (p < N_EDGES)
        csr_w[p] = dinv[csr_src[p]] * dinv[csr_dst[p]];
}

// ---------------- per-graph node counts via binary search (batch sorted) ------
__global__ __launch_bounds__(256) void k_cnt(const int* __restrict__ batch,
                                             float* __restrict__ cnt)
{
    int g = blockIdx.x * blockDim.x + threadIdx.x;
    if (g >= N_GRAPHS) return;
    int lo = 0, hi = N_NODES;
    while (lo < hi){ int m = (lo + hi) >> 1; if (batch[m] < g) lo = m + 1; else hi = m; }
    int lb = lo;
    lo = 0; hi = N_NODES;
    while (lo < hi){ int m = (lo + hi) >> 1; if (batch[m] < g + 1) lo = m + 1; else hi = m; }
    cnt[g] = (float)(lo - lb);
}

// ---------------- fp32 GEMM: out[N,128] = f(A)[N,128] @ W[128,128] ----------------
__global__ __launch_bounds__(256) void k_gemm(const float* __restrict__ A,
                                              const float* __restrict__ W,
                                              const float* __restrict__ scale,
                                              const float* __restrict__ shift,
                                              float* __restrict__ out,
                                              int useBn)
{
    __shared__ float ws[KT][D];
    __shared__ float hs[BR][KT + 4];
    int tid = threadIdx.x;
    int tx = tid & 15, ty = tid >> 4;
    long long rowBase = (long long)blockIdx.x * BR;
    float acc[2][8];
    #pragma unroll
    for (int r = 0; r < 2; r++)
        #pragma unroll
        for (int j = 0; j < 8; j++) acc[r][j] = 0.f;

    for (int k0 = 0; k0 < D; k0 += KT){
        #pragma unroll
        for (int j = 0; j < 4; j++){
            int f4 = tid + 256 * j;
            int kk = f4 >> 5;
            int cc = (f4 & 31) << 2;
            *(float4*)&ws[kk][cc] = *(const float4*)(W + (k0 + kk) * D + cc);
        }
        {
            int r  = tid >> 3;
            int cc = (tid & 7) << 2;
            float4 v = *(const float4*)(A + (rowBase + r) * D + k0 + cc);
            if (useBn){
                float4 sc = *(const float4*)(scale + k0 + cc);
                float4 sh = *(const float4*)(shift + k0 + cc);
                v.x = relu_f(fmaf(v.x, sc.x, sh.x));
                v.y = relu_f(fmaf(v.y, sc.y, sh.y));
                v.z = relu_f(fmaf(v.z, sc.z, sh.z));
                v.w = relu_f(fmaf(v.w, sc.w, sh.w));
            }
            *(float4*)&hs[r][cc] = v;
        }
        __syncthreads();
        #pragma unroll
        for (int k = 0; k < KT; k++){
            float4 w0 = *(const float4*)&ws[k][4 * tx];
            float4 w1 = *(const float4*)&ws[k][64 + 4 * tx];
            float a0 = hs[2 * ty][k];
            float a1 = hs[2 * ty + 1][k];
            acc[0][0] = fmaf(a0, w0.x, acc[0][0]);
            acc[0][1] = fmaf(a0, w0.y, acc[0][1]);
            acc[0][2] = fmaf(a0, w0.z, acc[0][2]);
            acc[0][3] = fmaf(a0, w0.w, acc[0][3]);
            acc[0][4] = fmaf(a0, w1.x, acc[0][4]);
            acc[0][5] = fmaf(a0, w1.y, acc[0][5]);
            acc[0][6] = fmaf(a0, w1.z, acc[0][6]);
            acc[0][7] = fmaf(a0, w1.w, acc[0][7]);
            acc[1][0] = fmaf(a1, w0.x, acc[1][0]);
            acc[1][1] = fmaf(a1, w0.y, acc[1][1]);
            acc[1][2] = fmaf(a1, w0.z, acc[1][2]);
            acc[1][3] = fmaf(a1, w0.w, acc[1][3]);
            acc[1][4] = fmaf(a1, w1.x, acc[1][4]);
            acc[1][5] = fmaf(a1, w1.y, acc[1][5]);
            acc[1][6] = fmaf(a1, w1.z, acc[1][6]);
            acc[1][7] = fmaf(a1, w1.w, acc[1][7]);
        }
        __syncthreads();
    }
    #pragma unroll
    for (int r = 0; r < 2; r++){
        long long row = rowBase + 2 * ty + r;
        float4 o0 = make_float4(acc[r][0], acc[r][1], acc[r][2], acc[r][3]);
        float4 o1 = make_float4(acc[r][4], acc[r][5], acc[r][6], acc[r][7]);
        *(float4*)(out + row * D + 4 * tx)      = o0;
        *(float4*)(out + row * D + 64 + 4 * tx) = o1;
    }
}

// ---------------- edge aggregation + bias (one wave per node, MLP=4) ----------
__global__ __launch_bounds__(256) void k_agg(const float* __restrict__ t,
                                             const int* __restrict__ row_ptr,
                                             const int* __restrict__ csr_src,
                                             const float* __restrict__ csr_w,
                                             const float* __restrict__ selfw,
                                             const float* __restrict__ bias,
                                             float* __restrict__ outb)
{
    int lane = threadIdx.x & 63;
    int i = (blockIdx.x * blockDim.x + threadIdx.x) >> 6;
    if (i >= N_NODES) return;
    const float2* t2 = (const float2*)t;
    int p0 = row_ptr[i], p1 = row_ptr[i + 1];
    float sw = selfw[i];
    float2 a = t2[(size_t)i * 64 + lane];
    float ax = a.x * sw, ay = a.y * sw;
    int p = p0;
    for (; p + 4 <= p1; p += 4){
        int   s0 = csr_src[p],   s1 = csr_src[p+1], s2 = csr_src[p+2], s3 = csr_src[p+3];
        float w0 = csr_w[p],     w1 = csr_w[p+1],   w2 = csr_w[p+2],   w3 = csr_w[p+3];
        float2 v0 = t2[(size_t)s0 * 64 + lane];
        float2 v1 = t2[(size_t)s1 * 64 + lane];
        float2 v2 = t2[(size_t)s2 * 64 + lane];
        float2 v3 = t2[(size_t)s3 * 64 + lane];
        ax = fmaf(w0, v0.x, ax); ay = fmaf(w0, v0.y, ay);
        ax = fmaf(w1, v1.x, ax); ay = fmaf(w1, v1.y, ay);
        ax = fmaf(w2, v2.x, ax); ay = fmaf(w2, v2.y, ay);
        ax = fmaf(w3, v3.x, ax); ay = fmaf(w3, v3.y, ay);
    }
    for (; p < p1; ++p){
        int s = csr_src[p];
        float w = csr_w[p];
        float2 v = t2[(size_t)s * 64 + lane];
        ax = fmaf(w, v.x, ax);
        ay = fmaf(w, v.y, ay);
    }
    float2 b2 = ((const float2*)bias)[lane];
    float2 o; o.x = ax + b2.x; o.y = ay + b2.y;
    ((float2*)outb)[(size_t)i * 64 + lane] = o;
}

// ---------------- BN stats: streaming scan of h -> S, Q ----------------
__global__ __launch_bounds__(256) void k_stats(const float* __restrict__ h,
                                               float* __restrict__ S,
                                               float* __restrict__ Q)
{
    __shared__ float sS[8][128];
    __shared__ float sQ[8][128];
    int g  = threadIdx.x >> 5;
    int c4 = threadIdx.x & 31;
    int r0 = blockIdx.x * 400;
    const float4* h4 = (const float4*)h;
    float4 s = make_float4(0.f, 0.f, 0.f, 0.f);
    float4 q = make_float4(0.f, 0.f, 0.f, 0.f);
    for (int r = r0 + g; r < r0 + 400; r += 8){
        float4 v = h4[(size_t)r * 32 + c4];
        s.x += v.x; s.y += v.y; s.z += v.z; s.w += v.w;
        q.x = fmaf(v.x, v.x, q.x);
        q.y = fmaf(v.y, v.y, q.y);
        q.z = fmaf(v.z, v.z, q.z);
        q.w = fmaf(v.w, v.w, q.w);
    }
    *(float4*)&sS[g][c4 * 4] = s;
    *(float4*)&sQ[g][c4 * 4] = q;
    __syncthreads();
    int f = threadIdx.x;
    if (f < 128){
        float acc = 0.f;
        #pragma unroll
        for (int j = 0; j < 8; j++) acc += sS[j][f];
        atomicAdd(&S[f], acc);
    } else {
        int f2 = f - 128;
        float acc = 0.f;
        #pragma unroll
        for (int j = 0; j < 8; j++) acc += sQ[j][f2];
        atomicAdd(&Q[f2], acc);
    }
}

// ---------------- BN finalize ----------------
__global__ __launch_bounds__(128) void k_fin(const float* __restrict__ S,
                                             const float* __restrict__ Q,
                                             const float* __restrict__ gamma,
                                             const float* __restrict__ beta,
                                             float* __restrict__ sc,
                                             float* __restrict__ sh)
{
    int f = threadIdx.x;
    float mean = S[f] * (1.0f / N_NODES);
    float var  = fmaxf(Q[f] * (1.0f / N_NODES) - mean * mean, 0.0f);
    float inv  = rsqrtf(var + EPSV);
    float g = gamma[f] * inv;
    sc[f] = g;
    sh[f] = beta[f] - mean * g;
}

// ---------------- pooled sum per graph ----------------
#define CHUNK 64
__global__ __launch_bounds__(256) void k_pool(const float* __restrict__ h,
                                              const int* __restrict__ batch,
                                              const float* __restrict__ sc,
                                              const float* __restrict__ sh,
                                              float* __restrict__ pool)
{
    int lane = threadIdx.x & 63;
    int wave = (blockIdx.x * blockDim.x + threadIdx.x) >> 6;
    int i0 = wave * CHUNK;
    if (i0 >= N_NODES) return;
    int i1 = min(N_NODES, i0 + CHUNK);
    const float2* h2 = (const float2*)h;
    float2 scv = ((const float2*)sc)[lane];
    float2 shv = ((const float2*)sh)[lane];
    int g = batch[i0];
    float ax = 0.f, ay = 0.f;
    for (int i = i0; i < i1; ++i){
        int gi = batch[i];
        if (gi != g){
            atomicAdd(&pool[g * 128 + 2 * lane],     ax);
            atomicAdd(&pool[g * 128 + 2 * lane + 1], ay);
            ax = 0.f; ay = 0.f; g = gi;
        }
        float2 v = h2[(size_t)i * 64 + lane];
        ax += relu_f(fmaf(v.x, scv.x, shv.x));
        ay += relu_f(fmaf(v.y, scv.y, shv.y));
    }
    atomicAdd(&pool[g * 128 + 2 * lane],     ax);
    atomicAdd(&pool[g * 128 + 2 * lane + 1], ay);
}

// ---------------- MLP head ----------------
__global__ __launch_bounds__(128) void k_head(const float* __restrict__ pool,
                                              const float* __restrict__ cnt,
                                              const float* __restrict__ W1,
                                              const float* __restrict__ b1,
                                              const float* __restrict__ W2,
                                              const float* __restrict__ b2,
                                              float* __restrict__ out)
{
    __shared__ float z[128];
    __shared__ float red[128];
    int g = blockIdx.x, f = threadIdx.x;
    float c = fmaxf(cnt[g], 1.0f);
    z[f] = pool[g * 128 + f] / c;
    __syncthreads();
    float a = b1[f];
    #pragma unroll 8
    for (int k = 0; k < 128; k++)
        a = fmaf(z[k], W1[k * 128 + f], a);
    a = relu_f(a);
    red[f] = a * W2[f];
    __syncthreads();
    for (int s2 = 64; s2 > 0; s2 >>= 1){
        if (f < s2) red[f] += red[f + s2];
        __syncthreads();
    }
    if (f == 0) out[g] = red[0] + b2[0];
}

extern "C" void kernel_launch(void* const* d_in, const int* in_sizes, int n_in,
                              void* d_out, int out_size, void* d_ws, size_t ws_size,
                              hipStream_t stream)
{
    const float* x      = (const float*)d_in[0];
    const int*   ei     = (const int*)d_in[1];
    const int*   batch  = (const int*)d_in[2];
    const float* Ws     = (const float*)d_in[3];
    const float* bs     = (const float*)d_in[4];
    const float* gammas = (const float*)d_in[5];
    const float* betas  = (const float*)d_in[6];
    const float* W1     = (const float*)d_in[7];
    const float* b1     = (const float*)d_in[8];
    const float* W2     = (const float*)d_in[9];
    const float* b2     = (const float*)d_in[10];
    float* out = (float*)d_out;

    const int* src = ei;
    const int* dst = ei + N_EDGES;

    char* w = (char*)d_ws;
    size_t off = 0;
    auto alloc = [&](size_t bytes) -> void* {
        void* p = w + off;
        off += (bytes + 255) & ~(size_t)255;
        return p;
    };
    int*   deg        = (int*)  alloc((size_t)N_NODES * 4);
    int*   row_ptr    = (int*)  alloc((size_t)(N_NODES + 1) * 4);
    float* dinv       = (float*)alloc((size_t)N_NODES * 4);
    float* selfw      = (float*)alloc((size_t)N_NODES * 4);
    int*   csr_src    = (int*)  alloc((size_t)N_EDGES * 4);
    float* csr_w      = (float*)alloc((size_t)N_EDGES * 4);
    int*   blockHist  = (int*)  alloc((size_t)NBLK * NBUK * 4);
    int*   colScan    = (int*)  alloc((size_t)NBLK * NBUK * 4);
    int*   bucketBase = (int*)  alloc((size_t)(NBUK + 1) * 4);
    size_t zoff = off;                       // --- zero-span start ---
    float* stats      = (float*)alloc(3 * 256 * 4);
    float* pool       = (float*)alloc((size_t)N_GRAPHS * 128 * 4);
    size_t zend = off;                       // --- zero-span end ---
    float* cnt        = (float*)alloc((size_t)N_GRAPHS * 4);
    float* ssh        = (float*)alloc(3 * 256 * 4);
    float* bufA       = (float*)alloc((size_t)N_NODES * 128 * 4);
    float* bufB       = (float*)alloc((size_t)N_NODES * 128 * 4);
    if (off > ws_size) return;

    // alias scratch (consumed before bufA/bufB are first written; stream-ordered)
    int2* ebuf    = (int2*)bufA;   // 6.4 MB < 51.2 MB
    int*  csr_dst = (int*)bufB;    // 3.2 MB < 51.2 MB

    hipMemsetAsync(w + zoff, 0, zend - zoff, stream);

    k_p1  <<<NBLK, 256, 0, stream>>>(dst, blockHist);
    k_p2  <<<1,    256, 0, stream>>>(blockHist, colScan, bucketBase, row_ptr);
    k_p3  <<<NBLK, 256, 0, stream>>>(src, dst, colScan, bucketBase, ebuf);
    k_p4  <<<NBUK, 256, 0, stream>>>(ebuf, bucketBase, deg, row_ptr, csr_src, csr_dst);
    k_dinv<<<(N_NODES + 255) / 256, 256, 0, stream>>>(deg, dinv, selfw);
    k_w   <<<(N_EDGES + 255) / 256, 256, 0, stream>>>(csr_src, csr_dst, dinv, csr_w);
    k_cnt <<<2, 256, 0, stream>>>(batch, cnt);

    const float* curIn = x;
    for (int l = 0; l < 3; l++){
        k_gemm<<<N_NODES / BR, 256, 0, stream>>>(
            curIn, Ws + l * 128 * 128,
            l ? ssh + (l - 1) * 256       : nullptr,
            l ? ssh + (l - 1) * 256 + 128 : nullptr,
            bufA, l ? 1 : 0);
        k_agg<<<25000, 256, 0, stream>>>(
            bufA, row_ptr, csr_src, csr_w, selfw,
            bs + l * 128, bufB);
        k_stats<<<250, 256, 0, stream>>>(
            bufB, stats + l * 256, stats + l * 256 + 128);
        k_fin<<<1, 128, 0, stream>>>(
            stats + l * 256, stats + l * 256 + 128,
            gammas + l * 128, betas + l * 128,
            ssh + l * 256, ssh + l * 256 + 128);
        curIn = bufB;
    }

    k_pool<<<391, 256, 0, stream>>>(bufB, batch, ssh + 2 * 256, ssh + 2 * 256 + 128, pool);
    k_head<<<512, 128, 0, stream>>>(pool, cnt, W1, b1, W2, b2, out);
}

// Round 4
// 624.710 us; speedup vs baseline: 1.5151x; 1.0017x over previous
//
#include <hip/hip_runtime.h>
#include <hip/hip_bf16.h>

#define N_NODES 100000
#define N_EDGES 800000
#define N_GRAPHS 512
#define D 128
#define EPSV 1e-5f
#define BR 32
#define KT 32

// radix-bucket CSR build params
#define NBLK 256          // edge-partition blocks
#define EPB  3125         // edges per block (256*3125 = 800000 exactly)
#define NBUK 196          // ceil(100000/512) buckets of 512 nodes (dst>>9)
#define MAXB 6144         // per-bucket LDS stash cap (mean 4096, sigma~64)

__device__ __forceinline__ float relu_f(float x){ return fmaxf(x, 0.0f); }

// ---------------- P1: per-block bucket histogram (LDS only) ----------------
__global__ __launch_bounds__(256) void k_p1(const int* __restrict__ dst,
                                            int* __restrict__ blockHist)
{
    __shared__ int h[NBUK];
    int j = blockIdx.x, t = threadIdx.x;
    if (t < NBUK) h[t] = 0;
    __syncthreads();
    int e0 = j * EPB;
    for (int e = e0 + t; e < e0 + EPB; e += 256)
        atomicAdd(&h[dst[e] >> 9], 1);
    __syncthreads();
    if (t < NBUK) blockHist[j * NBUK + t] = h[t];
}

// ---------------- P2: column scans + bucket bases (single block) ----------------
__global__ __launch_bounds__(256) void k_p2(const int* __restrict__ blockHist,
                                            int* __restrict__ colScan,
                                            int* __restrict__ bucketBase,
                                            int* __restrict__ row_ptr)
{
    __shared__ int sd[256];
    int b = threadIdx.x;
    int run = 0;
    if (b < NBUK){
        for (int j = 0; j < NBLK; j++){
            int v = blockHist[j * NBUK + b];
            colScan[j * NBUK + b] = run;   // edges of bucket b in blocks < j
            run += v;
        }
    }
    sd[b] = (b < NBUK) ? run : 0;
    __syncthreads();
    for (int off = 1; off < 256; off <<= 1){
        int v = (b >= off) ? sd[b - off] : 0;
        __syncthreads();
        sd[b] += v;
        __syncthreads();
    }
    if (b < NBUK) bucketBase[b] = sd[b] - run;   // exclusive
    if (b == 0){
        bucketBase[NBUK] = N_EDGES;
        row_ptr[N_NODES] = N_EDGES;
    }
}

// ---------------- P3: scatter edges into bucket-sorted ebuf (LDS cursors) ------
__global__ __launch_bounds__(256) void k_p3(const int* __restrict__ src,
                                            const int* __restrict__ dst,
                                            const int* __restrict__ colScan,
                                            const int* __restrict__ bucketBase,
                                            int2* __restrict__ ebuf)
{
    __shared__ int cur[NBUK];
    int j = blockIdx.x, t = threadIdx.x;
    if (t < NBUK) cur[t] = bucketBase[t] + colScan[j * NBUK + t];
    __syncthreads();
    int e0 = j * EPB;
    for (int e = e0 + t; e < e0 + EPB; e += 256){
        int s = src[e], d = dst[e];
        int pos = atomicAdd(&cur[d >> 9], 1);
        int2 v; v.x = s; v.y = d;
        ebuf[pos] = v;
    }
}

// ---------------- P4: per-bucket counting sort -> deg, row_ptr, CSR ----------
__global__ __launch_bounds__(256) void k_p4(const int2* __restrict__ ebuf,
                                            const int* __restrict__ bucketBase,
                                            int* __restrict__ deg,
                                            int* __restrict__ row_ptr,
                                            int* __restrict__ csr_src,
                                            int* __restrict__ csr_dst)
{
    __shared__ int2 stash[MAXB];
    __shared__ int bins[512];
    __shared__ int sd[256];
    int b = blockIdx.x, t = threadIdx.x;
    int base = bucketBase[b];
    int cntb = bucketBase[b + 1] - base;
    bool st = (cntb <= MAXB);
    bins[t] = 0; bins[t + 256] = 0;
    __syncthreads();
    for (int i = t; i < cntb; i += 256){
        int2 ed = ebuf[base + i];
        if (st) stash[i] = ed;
        atomicAdd(&bins[ed.y & 511], 1);
    }
    __syncthreads();
    int a0 = bins[2 * t], a1 = bins[2 * t + 1];
    int ps = a0 + a1;
    sd[t] = ps;
    __syncthreads();
    for (int off = 1; off < 256; off <<= 1){
        int v = (t >= off) ? sd[t - off] : 0;
        __syncthreads();
        sd[t] += v;
        __syncthreads();
    }
    int pex  = sd[t] - ps;        // exclusive over bin pairs
    int off0 = pex, off1 = pex + a0;
    int node = b * 512 + 2 * t;
    if (node < N_NODES)     { deg[node]     = a0; row_ptr[node]     = base + off0; }
    if (node + 1 < N_NODES) { deg[node + 1] = a1; row_ptr[node + 1] = base + off1; }
    __syncthreads();
    bins[2 * t] = off0; bins[2 * t + 1] = off1;   // repurpose as cursors
    __syncthreads();
    for (int i = t; i < cntb; i += 256){
        int2 ed = st ? stash[i] : ebuf[base + i];
        int pos = atomicAdd(&bins[ed.y & 511], 1);
        csr_src[base + pos] = ed.x;
        csr_dst[base + pos] = ed.y;
    }
}

__global__ __launch_bounds__(256) void k_dinv(const int* __restrict__ deg_i,
                                              float* __restrict__ dinv,
                                              float* __restrict__ selfw)
{
    int i = blockIdx.x * blockDim.x + threadIdx.x;
    if (i < N_NODES){
        float d = (float)(deg_i[i] + 1);
        dinv[i]  = rsqrtf(d);
        selfw[i] = 1.0f / d;
    }
}

// ---------------- edge weights: w = dinv[src]*dinv[dst] ----------------
__global__ __launch_bounds__(256) void k_w(const int* __restrict__ csr_src,
                                           const int* __restrict__ csr_dst,
                                           const float* __restrict__ dinv,
                                           float* __restrict__ csr_w)
{
    int p = blockIdx.x * 256 + threadIdx.x;
    if (p < N_EDGES)
        csr_w[p] = dinv[csr_src[p]] * dinv[csr_dst[p]];
}

// ---------------- per-graph node counts via binary search (batch sorted) ------
__global__ __launch_bounds__(256) void k_cnt(const int* __restrict__ batch,
                                             float* __restrict__ cnt)
{
    int g = blockIdx.x * blockDim.x + threadIdx.x;
    if (g >= N_GRAPHS) return;
    int lo = 0, hi = N_NODES;
    while (lo < hi){ int m = (lo + hi) >> 1; if (batch[m] < g) lo = m + 1; else hi = m; }
    int lb = lo;
    lo = 0; hi = N_NODES;
    while (lo < hi){ int m = (lo + hi) >> 1; if (batch[m] < g + 1) lo = m + 1; else hi = m; }
    cnt[g] = (float)(lo - lb);
}

// ---------------- fp32 GEMM: out[N,128] = f(A)[N,128] @ W[128,128] ----------------
__global__ __launch_bounds__(256) void k_gemm(const float* __restrict__ A,
                                              const float* __restrict__ W,
                                              const float* __restrict__ scale,
                                              const float* __restrict__ shift,
                                              float* __restrict__ out,
                                              int useBn)
{
    __shared__ float ws[KT][D];
    __shared__ float hs[BR][KT + 4];
    int tid = threadIdx.x;
    int tx = tid & 15, ty = tid >> 4;
    long long rowBase = (long long)blockIdx.x * BR;
    float acc[2][8];
    #pragma unroll
    for (int r = 0; r < 2; r++)
        #pragma unroll
        for (int j = 0; j < 8; j++) acc[r][j] = 0.f;

    for (int k0 = 0; k0 < D; k0 += KT){
        #pragma unroll
        for (int j = 0; j < 4; j++){
            int f4 = tid + 256 * j;
            int kk = f4 >> 5;
            int cc = (f4 & 31) << 2;
            *(float4*)&ws[kk][cc] = *(const float4*)(W + (k0 + kk) * D + cc);
        }
        {
            int r  = tid >> 3;
            int cc = (tid & 7) << 2;
            float4 v = *(const float4*)(A + (rowBase + r) * D + k0 + cc);
            if (useBn){
                float4 sc = *(const float4*)(scale + k0 + cc);
                float4 sh = *(const float4*)(shift + k0 + cc);
                v.x = relu_f(fmaf(v.x, sc.x, sh.x));
                v.y = relu_f(fmaf(v.y, sc.y, sh.y));
                v.z = relu_f(fmaf(v.z, sc.z, sh.z));
                v.w = relu_f(fmaf(v.w, sc.w, sh.w));
            }
            *(float4*)&hs[r][cc] = v;
        }
        __syncthreads();
        #pragma unroll
        for (int k = 0; k < KT; k++){
            float4 w0 = *(const float4*)&ws[k][4 * tx];
            float4 w1 = *(const float4*)&ws[k][64 + 4 * tx];
            float a0 = hs[2 * ty][k];
            float a1 = hs[2 * ty + 1][k];
            acc[0][0] = fmaf(a0, w0.x, acc[0][0]);
            acc[0][1] = fmaf(a0, w0.y, acc[0][1]);
            acc[0][2] = fmaf(a0, w0.z, acc[0][2]);
            acc[0][3] = fmaf(a0, w0.w, acc[0][3]);
            acc[0][4] = fmaf(a0, w1.x, acc[0][4]);
            acc[0][5] = fmaf(a0, w1.y, acc[0][5]);
            acc[0][6] = fmaf(a0, w1.z, acc[0][6]);
            acc[0][7] = fmaf(a0, w1.w, acc[0][7]);
            acc[1][0] = fmaf(a1, w0.x, acc[1][0]);
            acc[1][1] = fmaf(a1, w0.y, acc[1][1]);
            acc[1][2] = fmaf(a1, w0.z, acc[1][2]);
            acc[1][3] = fmaf(a1, w0.w, acc[1][3]);
            acc[1][4] = fmaf(a1, w1.x, acc[1][4]);
            acc[1][5] = fmaf(a1, w1.y, acc[1][5]);
            acc[1][6] = fmaf(a1, w1.z, acc[1][6]);
            acc[1][7] = fmaf(a1, w1.w, acc[1][7]);
        }
        __syncthreads();
    }
    #pragma unroll
    for (int r = 0; r < 2; r++){
        long long row = rowBase + 2 * ty + r;
        float4 o0 = make_float4(acc[r][0], acc[r][1], acc[r][2], acc[r][3]);
        float4 o1 = make_float4(acc[r][4], acc[r][5], acc[r][6], acc[r][7]);
        *(float4*)(out + row * D + 4 * tx)      = o0;
        *(float4*)(out + row * D + 64 + 4 * tx) = o1;
    }
}

// ---------------- edge aggregation + bias (one wave per node, MLP=8) ----------
__global__ __launch_bounds__(256) void k_agg(const float* __restrict__ t,
                                             const int* __restrict__ row_ptr,
                                             const int* __restrict__ csr_src,
                                             const float* __restrict__ csr_w,
                                             const float* __restrict__ selfw,
                                             const float* __restrict__ bias,
                                             float* __restrict__ outb)
{
    int lane = threadIdx.x & 63;
    int i = (blockIdx.x * blockDim.x + threadIdx.x) >> 6;
    if (i >= N_NODES) return;
    const float2* t2 = (const float2*)t;
    int p0 = row_ptr[i], p1 = row_ptr[i + 1];
    float sw = selfw[i];
    float2 a = t2[(size_t)i * 64 + lane];
    float ax = a.x * sw, ay = a.y * sw;
    int p = p0;
    // 8-wide batches: 8 independent 512B row-gathers in flight
    for (; p + 8 <= p1; p += 8){
        int s[8]; float wv[8];
        #pragma unroll
        for (int j = 0; j < 8; j++){ s[j] = csr_src[p + j]; }
        #pragma unroll
        for (int j = 0; j < 8; j++){ wv[j] = csr_w[p + j]; }
        float2 v[8];
        #pragma unroll
        for (int j = 0; j < 8; j++) v[j] = t2[(size_t)s[j] * 64 + lane];
        #pragma unroll
        for (int j = 0; j < 8; j++){
            ax = fmaf(wv[j], v[j].x, ax);
            ay = fmaf(wv[j], v[j].y, ay);
        }
    }
    for (; p + 4 <= p1; p += 4){
        int   s0 = csr_src[p],   s1 = csr_src[p+1], s2 = csr_src[p+2], s3 = csr_src[p+3];
        float w0 = csr_w[p],     w1 = csr_w[p+1],   w2 = csr_w[p+2],   w3 = csr_w[p+3];
        float2 v0 = t2[(size_t)s0 * 64 + lane];
        float2 v1 = t2[(size_t)s1 * 64 + lane];
        float2 v2 = t2[(size_t)s2 * 64 + lane];
        float2 v3 = t2[(size_t)s3 * 64 + lane];
        ax = fmaf(w0, v0.x, ax); ay = fmaf(w0, v0.y, ay);
        ax = fmaf(w1, v1.x, ax); ay = fmaf(w1, v1.y, ay);
        ax = fmaf(w2, v2.x, ax); ay = fmaf(w2, v2.y, ay);
        ax = fmaf(w3, v3.x, ax); ay = fmaf(w3, v3.y, ay);
    }
    for (; p < p1; ++p){
        int s = csr_src[p];
        float w = csr_w[p];
        float2 v = t2[(size_t)s * 64 + lane];
        ax = fmaf(w, v.x, ax);
        ay = fmaf(w, v.y, ay);
    }
    float2 b2 = ((const float2*)bias)[lane];
    float2 o; o.x = ax + b2.x; o.y = ay + b2.y;
    ((float2*)outb)[(size_t)i * 64 + lane] = o;
}

// ---------------- BN stats: streaming scan of h -> S, Q ----------------
__global__ __launch_bounds__(256) void k_stats(const float* __restrict__ h,
                                               float* __restrict__ S,
                                               float* __restrict__ Q)
{
    __shared__ float sS[8][128];
    __shared__ float sQ[8][128];
    int g  = threadIdx.x >> 5;
    int c4 = threadIdx.x & 31;
    int r0 = blockIdx.x * 400;
    const float4* h4 = (const float4*)h;
    float4 s = make_float4(0.f, 0.f, 0.f, 0.f);
    float4 q = make_float4(0.f, 0.f, 0.f, 0.f);
    for (int r = r0 + g; r < r0 + 400; r += 8){
        float4 v = h4[(size_t)r * 32 + c4];
        s.x += v.x; s.y += v.y; s.z += v.z; s.w += v.w;
        q.x = fmaf(v.x, v.x, q.x);
        q.y = fmaf(v.y, v.y, q.y);
        q.z = fmaf(v.z, v.z, q.z);
        q.w = fmaf(v.w, v.w, q.w);
    }
    *(float4*)&sS[g][c4 * 4] = s;
    *(float4*)&sQ[g][c4 * 4] = q;
    __syncthreads();
    int f = threadIdx.x;
    if (f < 128){
        float acc = 0.f;
        #pragma unroll
        for (int j = 0; j < 8; j++) acc += sS[j][f];
        atomicAdd(&S[f], acc);
    } else {
        int f2 = f - 128;
        float acc = 0.f;
        #pragma unroll
        for (int j = 0; j < 8; j++) acc += sQ[j][f2];
        atomicAdd(&Q[f2], acc);
    }
}

// ---------------- BN finalize ----------------
__global__ __launch_bounds__(128) void k_fin(const float* __restrict__ S,
                                             const float* __restrict__ Q,
                                             const float* __restrict__ gamma,
                                             const float* __restrict__ beta,
                                             float* __restrict__ sc,
                                             float* __restrict__ sh)
{
    int f = threadIdx.x;
    float mean = S[f] * (1.0f / N_NODES);
    float var  = fmaxf(Q[f] * (1.0f / N_NODES) - mean * mean, 0.0f);
    float inv  = rsqrtf(var + EPSV);
    float g = gamma[f] * inv;
    sc[f] = g;
    sh[f] = beta[f] - mean * g;
}

// ---------------- pooled sum per graph ----------------
#define CHUNK 64
__global__ __launch_bounds__(256) void k_pool(const float* __restrict__ h,
                                              const int* __restrict__ batch,
                                              const float* __restrict__ sc,
                                              const float* __restrict__ sh,
                                              float* __restrict__ pool)
{
    int lane = threadIdx.x & 63;
    int wave = (blockIdx.x * blockDim.x + threadIdx.x) >> 6;
    int i0 = wave * CHUNK;
    if (i0 >= N_NODES) return;
    int i1 = min(N_NODES, i0 + CHUNK);
    const float2* h2 = (const float2*)h;
    float2 scv = ((const float2*)sc)[lane];
    float2 shv = ((const float2*)sh)[lane];
    int g = batch[i0];
    float ax = 0.f, ay = 0.f;
    for (int i = i0; i < i1; ++i){
        int gi = batch[i];
        if (gi != g){
            atomicAdd(&pool[g * 128 + 2 * lane],     ax);
            atomicAdd(&pool[g * 128 + 2 * lane + 1], ay);
            ax = 0.f; ay = 0.f; g = gi;
        }
        float2 v = h2[(size_t)i * 64 + lane];
        ax += relu_f(fmaf(v.x, scv.x, shv.x));
        ay += relu_f(fmaf(v.y, scv.y, shv.y));
    }
    atomicAdd(&pool[g * 128 + 2 * lane],     ax);
    atomicAdd(&pool[g * 128 + 2 * lane + 1], ay);
}

// ---------------- MLP head ----------------
__global__ __launch_bounds__(128) void k_head(const float* __restrict__ pool,
                                              const float* __restrict__ cnt,
                                              const float* __restrict__ W1,
                                              const float* __restrict__ b1,
                                              const float* __restrict__ W2,
                                              const float* __restrict__ b2,
                                              float* __restrict__ out)
{
    __shared__ float z[128];
    __shared__ float red[128];
    int g = blockIdx.x, f = threadIdx.x;
    float c = fmaxf(cnt[g], 1.0f);
    z[f] = pool[g * 128 + f] / c;
    __syncthreads();
    float a = b1[f];
    #pragma unroll 8
    for (int k = 0; k < 128; k++)
        a = fmaf(z[k], W1[k * 128 + f], a);
    a = relu_f(a);
    red[f] = a * W2[f];
    __syncthreads();
    for (int s2 = 64; s2 > 0; s2 >>= 1){
        if (f < s2) red[f] += red[f + s2];
        __syncthreads();
    }
    if (f == 0) out[g] = red[0] + b2[0];
}

extern "C" void kernel_launch(void* const* d_in, const int* in_sizes, int n_in,
                              void* d_out, int out_size, void* d_ws, size_t ws_size,
                              hipStream_t stream)
{
    const float* x      = (const float*)d_in[0];
    const int*   ei     = (const int*)d_in[1];
    const int*   batch  = (const int*)d_in[2];
    const float* Ws     = (const float*)d_in[3];
    const float* bs     = (const float*)d_in[4];
    const float* gammas = (const float*)d_in[5];
    const float* betas  = (const float*)d_in[6];
    const float* W1     = (const float*)d_in[7];
    const float* b1     = (const float*)d_in[8];
    const float* W2     = (const float*)d_in[9];
    const float* b2     = (const float*)d_in[10];
    float* out = (float*)d_out;

    const int* src = ei;
    const int* dst = ei + N_EDGES;

    char* w = (char*)d_ws;
    size_t off = 0;
    auto alloc = [&](size_t bytes) -> void* {
        void* p = w + off;
        off += (bytes + 255) & ~(size_t)255;
        return p;
    };
    int*   deg        = (int*)  alloc((size_t)N_NODES * 4);
    int*   row_ptr    = (int*)  alloc((size_t)(N_NODES + 1) * 4);
    float* dinv       = (float*)alloc((size_t)N_NODES * 4);
    float* selfw      = (float*)alloc((size_t)N_NODES * 4);
    int*   csr_src    = (int*)  alloc((size_t)N_EDGES * 4);
    float* csr_w      = (float*)alloc((size_t)N_EDGES * 4);
    int*   blockHist  = (int*)  alloc((size_t)NBLK * NBUK * 4);
    int*   colScan    = (int*)  alloc((size_t)NBLK * NBUK * 4);
    int*   bucketBase = (int*)  alloc((size_t)(NBUK + 1) * 4);
    size_t zoff = off;                       // --- zero-span start ---
    float* stats      = (float*)alloc(3 * 256 * 4);
    float* pool       = (float*)alloc((size_t)N_GRAPHS * 128 * 4);
    size_t zend = off;                       // --- zero-span end ---
    float* cnt        = (float*)alloc((size_t)N_GRAPHS * 4);
    float* ssh        = (float*)alloc(3 * 256 * 4);
    float* bufA       = (float*)alloc((size_t)N_NODES * 128 * 4);
    float* bufB       = (float*)alloc((size_t)N_NODES * 128 * 4);
    if (off > ws_size) return;

    // alias scratch (consumed before bufA/bufB are first written; stream-ordered)
    int2* ebuf    = (int2*)bufA;   // 6.4 MB < 51.2 MB
    int*  csr_dst = (int*)bufB;    // 3.2 MB < 51.2 MB

    hipMemsetAsync(w + zoff, 0, zend - zoff, stream);

    k_p1  <<<NBLK, 256, 0, stream>>>(dst, blockHist);
    k_p2  <<<1,    256, 0, stream>>>(blockHist, colScan, bucketBase, row_ptr);
    k_p3  <<<NBLK, 256, 0, stream>>>(src, dst, colScan, bucketBase, ebuf);
    k_p4  <<<NBUK, 256, 0, stream>>>(ebuf, bucketBase, deg, row_ptr, csr_src, csr_dst);
    k_dinv<<<(N_NODES + 255) / 256, 256, 0, stream>>>(deg, dinv, selfw);
    k_w   <<<(N_EDGES + 255) / 256, 256, 0, stream>>>(csr_src, csr_dst, dinv, csr_w);
    k_cnt <<<2, 256, 0, stream>>>(batch, cnt);

    const float* curIn = x;
    for (int l = 0; l < 3; l++){
        k_gemm<<<N_NODES / BR, 256, 0, stream>>>(
            curIn, Ws + l * 128 * 128,
            l ? ssh + (l - 1) * 256       : nullptr,
            l ? ssh + (l - 1) * 256 + 128 : nullptr,
            bufA, l ? 1 : 0);
        k_agg<<<25000, 256, 0, stream>>>(
            bufA, row_ptr, csr_src, csr_w, selfw,
            bs + l * 128, bufB);
        k_stats<<<250, 256, 0, stream>>>(
            bufB, stats + l * 256, stats + l * 256 + 128);
        k_fin<<<1, 128, 0, stream>>>(
            stats + l * 256, stats + l * 256 + 128,
            gammas + l * 128, betas + l * 128,
            ssh + l * 256, ssh + l * 256 + 128);
        curIn = bufB;
    }

    k_pool<<<391, 256, 0, stream>>>(bufB, batch, ssh + 2 * 256, ssh + 2 * 256 + 128, pool);
    k_head<<<512, 128, 0, stream>>>(pool, cnt, W1, b1, W2, b2, out);
}